// Round 10
// baseline (173.071 us; speedup 1.0000x reference)
//
#include <hip/hip_runtime.h>
#include <cstdint>
#include <cstddef>

// Problem constants (fixed by the bench harness)
#define B_ 2
#define N_ 16384
#define K_ 16
#define C_ 128

typedef __attribute__((ext_vector_type(8))) short  bf16x8;
typedef __attribute__((ext_vector_type(4))) float  f32x4;

// bf16 (ushort bits) -> fp32, exact
__device__ __forceinline__ float bfu_lo(uint32_t w) { return __uint_as_float(w << 16); }
__device__ __forceinline__ float bfu_hi(uint32_t w) { return __uint_as_float(w & 0xffff0000u); }

// fp32 -> bf16 bits, round-to-nearest-even
__device__ __forceinline__ ushort f32_to_bf16_rne(float x) {
    uint32_t u = __float_as_uint(x);
    u += 0x7FFFu + ((u >> 16) & 1u);
    return (ushort)(u >> 16);
}
__device__ __forceinline__ uint32_t pack_bf16x2(float lo, float hi) {
    return (uint32_t)f32_to_bf16_rne(lo) | ((uint32_t)f32_to_bf16_rne(hi) << 16);
}

// fp8 e5m2 via the f16-prefix trick (e5m2 = top byte of IEEE f16).
__device__ __forceinline__ uint32_t e5m2_enc(float x) {
    union { _Float16 h; ushort u; } cv;
    cv.h = (_Float16)x;                       // RNE f32->f16 (hw)
    ushort h = (ushort)(cv.u + 0x7Fu + ((cv.u >> 8) & 1u));  // RNE to top byte
    return (uint32_t)(h >> 8) & 0xFFu;
}
__device__ __forceinline__ float e5m2_dec(uint32_t byteval) {
    union { _Float16 h; ushort u; } cv;
    cv.u = (ushort)(byteval << 8);
    return (float)cv.h;
}

// LDS swizzle: element offset of (row, c) in a [128 row][128 c] bf16 tile.
__device__ __forceinline__ int xswz(int row, int c) {
    return row * 128 + ((((c >> 3) ^ (row & 7)) << 3) | (c & 7));
}

// ---------------------------------------------------------------------------
// Kernel 1 (round-10): QKV projections via MFMA.
//   z=0: Q from spa (bf16 out). z=1: K (fp8 out) AND V (bf16 out) from ONE
//   staged spe tile -- spe is read once, not twice (traffic 68 -> 52 MB).
//   W fragments live in REGISTERS (loaded once per block, converted inline,
//   issued before the barrier) -- no ws LDS buffer, so LDS/block drops
//   64->32 KB and 4-5 blocks/CU can overlap staging with compute.
// Block tile 128o x 128n, 512 thr = 8 waves (wave tile 32o x 64n).
// grid (N/128, B, 2).
// ---------------------------------------------------------------------------
__global__ __launch_bounds__(512) void qkv_gemm(
    const float* __restrict__ spa, const float* __restrict__ spe,
    const float* __restrict__ wq, const float* __restrict__ wk,
    const float* __restrict__ wv, const float* __restrict__ wvb,
    ushort* __restrict__ Qt16, uint8_t* __restrict__ Kt8, ushort* __restrict__ Vt16)
{
    const int nt  = blockIdx.x * 128;
    const int b   = blockIdx.y;
    const bool isQ = (blockIdx.z == 0);
    const float* X = isQ ? spa : spe;

    __shared__ ushort xs[128 * 128];   // X^T tile [n][c] bf16, swizzled, 32 KB

    const int t    = threadIdx.x;
    const int w    = t >> 6;           // wave 0..7
    const int lane = t & 63;
    const int l15  = lane & 15;
    const int l4   = lane >> 4;        // 0..3
    const int ow   = (w & 3) * 32;     // wave o-base
    const int nw   = (w >> 2) * 64;    // wave n-base

    // ---- stage X tile [128 c][128 n] -> xs bf16 transposed+swizzled ----
    {
        const int c  = t >> 2;               // 0..127
        const int nq = (t & 3) * 32;         // 32 n per thread
        const float* xrow = X + ((size_t)b * C_ + c) * N_ + nt + nq;
        #pragma unroll
        for (int q = 0; q < 8; ++q) {
            float4 v = ((const float4*)xrow)[q];
            const int n = nq + q * 4;
            xs[xswz(n + 0, c)] = f32_to_bf16_rne(v.x);
            xs[xswz(n + 1, c)] = f32_to_bf16_rne(v.y);
            xs[xswz(n + 2, c)] = f32_to_bf16_rne(v.z);
            xs[xswz(n + 3, c)] = f32_to_bf16_rne(v.w);
        }
    }

    // ---- W fragments -> registers (global fp32, convert once; issued
    //      before the barrier so the loads overlap the LDS staging) ----
    // A-frag lane mapping: row = ow + of*16 + l15, c = kc*32 + l4*8 + 0..7
    auto load_wfrags = [&](const float* __restrict__ W, bf16x8 wf[2][4]) {
        #pragma unroll
        for (int of = 0; of < 2; ++of) {
            #pragma unroll
            for (int kc = 0; kc < 4; ++kc) {
                const float* wp = W + (size_t)(ow + of * 16 + l15) * C_ + kc * 32 + l4 * 8;
                float4 a  = *(const float4*)wp;
                float4 b4 = *(const float4*)(wp + 4);
                bf16x8 f;
                f[0] = (short)f32_to_bf16_rne(a.x);
                f[1] = (short)f32_to_bf16_rne(a.y);
                f[2] = (short)f32_to_bf16_rne(a.z);
                f[3] = (short)f32_to_bf16_rne(a.w);
                f[4] = (short)f32_to_bf16_rne(b4.x);
                f[5] = (short)f32_to_bf16_rne(b4.y);
                f[6] = (short)f32_to_bf16_rne(b4.z);
                f[7] = (short)f32_to_bf16_rne(b4.w);
                wf[of][kc] = f;
            }
        }
    };

    if (isQ) {
        bf16x8 wfq[2][4];
        load_wfrags(wq, wfq);
        __syncthreads();

        f32x4 acc[2][4];
        #pragma unroll
        for (int of = 0; of < 2; ++of)
            #pragma unroll
            for (int nf = 0; nf < 4; ++nf)
                acc[of][nf] = (f32x4){0.f, 0.f, 0.f, 0.f};

        #pragma unroll
        for (int kc = 0; kc < 4; ++kc) {
            const int cb = kc * 32 + l4 * 8;
            bf16x8 bfr[4];
            #pragma unroll
            for (int nf = 0; nf < 4; ++nf)
                bfr[nf] = *(__shared__ bf16x8*)&xs[xswz(nw + nf * 16 + l15, cb)];
            #pragma unroll
            for (int of = 0; of < 2; ++of)
                #pragma unroll
                for (int nf = 0; nf < 4; ++nf)
                    acc[of][nf] = __builtin_amdgcn_mfma_f32_16x16x32_bf16(
                        wfq[of][kc], bfr[nf], acc[of][nf], 0, 0, 0);
        }

        #pragma unroll
        for (int of = 0; of < 2; ++of) {
            const int o0r = ow + of * 16 + l4 * 4;
            #pragma unroll
            for (int nf = 0; nf < 4; ++nf) {
                const int n = nt + nw + nf * 16 + l15;
                uint2 pk;
                pk.x = pack_bf16x2(acc[of][nf][0], acc[of][nf][1]);
                pk.y = pack_bf16x2(acc[of][nf][2], acc[of][nf][3]);
                *(uint2*)(Qt16 + ((size_t)b * N_ + n) * C_ + o0r) = pk;
            }
        }
    } else {
        bf16x8 wfk[2][4], wfv[2][4];
        load_wfrags(wk, wfk);
        load_wfrags(wv, wfv);
        __syncthreads();

        f32x4 acck[2][4], accv[2][4];
        #pragma unroll
        for (int of = 0; of < 2; ++of)
            #pragma unroll
            for (int nf = 0; nf < 4; ++nf) {
                acck[of][nf] = (f32x4){0.f, 0.f, 0.f, 0.f};
                accv[of][nf] = (f32x4){0.f, 0.f, 0.f, 0.f};
            }

        #pragma unroll
        for (int kc = 0; kc < 4; ++kc) {
            const int cb = kc * 32 + l4 * 8;
            bf16x8 bfr[4];
            #pragma unroll
            for (int nf = 0; nf < 4; ++nf)
                bfr[nf] = *(__shared__ bf16x8*)&xs[xswz(nw + nf * 16 + l15, cb)];
            #pragma unroll
            for (int of = 0; of < 2; ++of)
                #pragma unroll
                for (int nf = 0; nf < 4; ++nf) {
                    acck[of][nf] = __builtin_amdgcn_mfma_f32_16x16x32_bf16(
                        wfk[of][kc], bfr[nf], acck[of][nf], 0, 0, 0);
                    accv[of][nf] = __builtin_amdgcn_mfma_f32_16x16x32_bf16(
                        wfv[of][kc], bfr[nf], accv[of][nf], 0, 0, 0);
                }
        }

        #pragma unroll
        for (int of = 0; of < 2; ++of) {
            const int o0r = ow + of * 16 + l4 * 4;
            const float4 bv = *(const float4*)(wvb + o0r);
            #pragma unroll
            for (int nf = 0; nf < 4; ++nf) {
                const int n = nt + nw + nf * 16 + l15;
                // K -> fp8 e5m2
                uint32_t w8 = e5m2_enc(acck[of][nf][0])
                            | (e5m2_enc(acck[of][nf][1]) << 8)
                            | (e5m2_enc(acck[of][nf][2]) << 16)
                            | (e5m2_enc(acck[of][nf][3]) << 24);
                *(uint32_t*)(Kt8 + ((size_t)b * N_ + n) * C_ + o0r) = w8;
                // V -> bf16 (+bias)
                uint2 pk;
                pk.x = pack_bf16x2(accv[of][nf][0] + bv.x, accv[of][nf][1] + bv.y);
                pk.y = pack_bf16x2(accv[of][nf][2] + bv.z, accv[of][nf][3] + bv.w);
                *(uint2*)(Vt16 + ((size_t)b * N_ + n) * C_ + o0r) = pk;
            }
        }
    }
}

// ---------------------------------------------------------------------------
// Kernel 2: gather + scores + softmax + weighted V-sum. (byte-identical r9 —
// control; r9's 2-deep pipeline kept, it was neutral.)
// ---------------------------------------------------------------------------
struct GR {
    uint4    ka, kb;          // 32 fp8 K channels for this lane's k-group
    uint32_t vv[16];          // V bf16-pair per k, channels 2l/2l+1
    float    nc0, nc1, nc2;   // neighbor coords for this lane's k-group
};

__device__ __forceinline__ void gather_issue(
    GR& g2, const int (*idx_s)[16], int nl, int b,
    const uint8_t* __restrict__ Kt8, const ushort* __restrict__ Vt16,
    const float* __restrict__ coord, int gk, int sub, int lane)
{
    const int idxg = idx_s[nl][gk];
    const uint4* kp = (const uint4*)(Kt8 + ((size_t)(b * N_ + idxg)) * C_ + sub * 32);
    g2.ka = kp[0];
    g2.kb = kp[1];
    #pragma unroll
    for (int k = 0; k < 16; ++k) {
        const int vid = idx_s[nl][k];
        g2.vv[k] = ((const uint32_t*)(Vt16 + ((size_t)(b * N_ + vid)) * C_))[lane];
    }
    const float* ncp = coord + ((size_t)(b * N_ + idxg)) * 3;
    g2.nc0 = ncp[0];
    g2.nc1 = ncp[1];
    g2.nc2 = ncp[2];
}

__global__ __launch_bounds__(256) void attn_fuse(
    const float* __restrict__ coord, const int* __restrict__ nbr,
    const ushort* __restrict__ Qt16, const uint8_t* __restrict__ Kt8,
    const ushort* __restrict__ Vt16,
    const float* __restrict__ pw1, const float* __restrict__ pb1,
    const float* __restrict__ pg,  const float* __restrict__ pbeta,
    const float* __restrict__ pmu, const float* __restrict__ pvar,
    const float* __restrict__ pw2, const float* __restrict__ pb2,
    const float* __restrict__ sw1, const float* __restrict__ sb1,
    const float* __restrict__ sg,  const float* __restrict__ sbeta,
    const float* __restrict__ smu, const float* __restrict__ svar,
    const float* __restrict__ sw2, const float* __restrict__ sb2,
    float* __restrict__ out)
{
    const int bid  = blockIdx.x;
    const int b    = bid >> 10;               // 1024 blocks per batch
    const int n0   = (bid & 1023) << 4;       // 16-n tile
    const int t    = threadIdx.x;
    const int w    = t >> 6;                  // wave 0..3
    const int lane = t & 63;
    const int g    = lane >> 2;               // k index 0..15
    const int sub  = lane & 3;                // channel quarter

    __shared__ float qs[16][132];
    __shared__ int   idx_s[16][16];
    __shared__ float cs[16][3];
    __shared__ float ot[128][17];

    // ---- stage ----
    {
        const int n = t >> 4, c0 = (t & 15) * 8;
        uint4 qw = *(const uint4*)(Qt16 + ((size_t)(b * N_ + n0 + n)) * C_ + c0);
        qs[n][c0 + 0] = bfu_lo(qw.x); qs[n][c0 + 1] = bfu_hi(qw.x);
        qs[n][c0 + 2] = bfu_lo(qw.y); qs[n][c0 + 3] = bfu_hi(qw.y);
        qs[n][c0 + 4] = bfu_lo(qw.z); qs[n][c0 + 5] = bfu_hi(qw.z);
        qs[n][c0 + 6] = bfu_lo(qw.w); qs[n][c0 + 7] = bfu_hi(qw.w);
        idx_s[t >> 4][t & 15] = nbr[((size_t)(b * N_ + n0 + (t >> 4))) * K_ + (t & 15)];
        if (t < 48) cs[t / 3][t % 3] = coord[((size_t)(b * N_ + n0 + t / 3)) * 3 + (t % 3)];
    }
    __syncthreads();

    // ---- uniform params (BN folded) ----
    float pinv[3], pofs[3], w1r[3][3], w2r[3], pb1r[3];
    #pragma unroll
    for (int o = 0; o < 3; ++o) {
        float inv = pg[o] / sqrtf(pvar[o] + 1e-5f);
        pinv[o] = inv;
        pofs[o] = pbeta[o] - pmu[o] * inv;
        pb1r[o] = pb1[o];
        w2r[o]  = pw2[o];
        #pragma unroll
        for (int i2 = 0; i2 < 3; ++i2) w1r[o][i2] = pw1[o * 3 + i2];
    }
    const float pb2v = pb2[0];
    float sinv[2], sofs[2], sb1r[2];
    #pragma unroll
    for (int o = 0; o < 2; ++o) {
        float inv = sg[o] / sqrtf(svar[o] + 1e-5f);
        sinv[o] = inv;
        sofs[o] = sbeta[o] - smu[o] * inv;
        sb1r[o] = sb1[o];
    }
    const float sw1r[4] = {sw1[0], sw1[1], sw1[2], sw1[3]};
    const float sw2r[2] = {sw2[0], sw2[1]};
    const float sb2v = sb2[0];
    const float inv_sqrtC = 0.088388347648318447f;  // 1/sqrt(128)

    auto compute = [&](int nl, GR& gr) {
        const float* qrow = &qs[nl][sub * 32];
        float acc = 0.f;
        {
            const uint32_t wds[8] = {gr.ka.x, gr.ka.y, gr.ka.z, gr.ka.w,
                                     gr.kb.x, gr.kb.y, gr.kb.z, gr.kb.w};
            #pragma unroll
            for (int j = 0; j < 8; ++j) {
                const uint32_t ww = wds[j];
                acc = fmaf(qrow[j * 4 + 0], e5m2_dec(ww & 0xffu), acc);
                acc = fmaf(qrow[j * 4 + 1], e5m2_dec((ww >> 8) & 0xffu), acc);
                acc = fmaf(qrow[j * 4 + 2], e5m2_dec((ww >> 16) & 0xffu), acc);
                acc = fmaf(qrow[j * 4 + 3], e5m2_dec(ww >> 24), acc);
            }
        }
        acc += __shfl_xor(acc, 1);
        acc += __shfl_xor(acc, 2);
        const float sfeat = acc * inv_sqrtC;

        float d0 = gr.nc0 - cs[nl][0], d1 = gr.nc1 - cs[nl][1], d2 = gr.nc2 - cs[nl][2];
        float g0 = expf(-2.f * d0 * d0);
        float g1 = expf(-2.f * d1 * d1);
        float g2 = expf(-2.f * d2 * d2);
        float h0 = fmaf(w1r[0][0], g0, fmaf(w1r[0][1], g1, fmaf(w1r[0][2], g2, pb1r[0])));
        float h1 = fmaf(w1r[1][0], g0, fmaf(w1r[1][1], g1, fmaf(w1r[1][2], g2, pb1r[1])));
        float h2 = fmaf(w1r[2][0], g0, fmaf(w1r[2][1], g1, fmaf(w1r[2][2], g2, pb1r[2])));
        h0 = fmaxf(fmaf(h0, pinv[0], pofs[0]), 0.f);
        h1 = fmaxf(fmaf(h1, pinv[1], pofs[1]), 0.f);
        h2 = fmaxf(fmaf(h2, pinv[2], pofs[2]), 0.f);
        const float scoord = fmaf(w2r[0], h0, fmaf(w2r[1], h1, fmaf(w2r[2], h2, pb2v)));

        float t0 = fmaf(sw1r[0], scoord, fmaf(sw1r[1], sfeat, sb1r[0]));
        t0 = fmaxf(fmaf(t0, sinv[0], sofs[0]), 0.f);
        float t1 = fmaf(sw1r[2], scoord, fmaf(sw1r[3], sfeat, sb1r[1]));
        t1 = fmaxf(fmaf(t1, sinv[1], sofs[1]), 0.f);
        float s = fmaf(sw2r[0], t0, fmaf(sw2r[1], t1, sb2v));

        float m = s;
        m = fmaxf(m, __shfl_xor(m, 4));
        m = fmaxf(m, __shfl_xor(m, 8));
        m = fmaxf(m, __shfl_xor(m, 16));
        m = fmaxf(m, __shfl_xor(m, 32));
        float e = expf(s - m);
        float den = e;
        den += __shfl_xor(den, 4);
        den += __shfl_xor(den, 8);
        den += __shfl_xor(den, 16);
        den += __shfl_xor(den, 32);
        const float attn = e / den;

        float a0 = 0.f, a1 = 0.f;
        #pragma unroll
        for (int k = 0; k < 16; ++k) {
            const float ak = __shfl(attn, k << 2);
            a0 = fmaf(ak, bfu_lo(gr.vv[k]), a0);
            a1 = fmaf(ak, bfu_hi(gr.vv[k]), a1);
        }
        ot[2 * lane][nl]     = a0;
        ot[2 * lane + 1][nl] = a1;
    };

    // ---- 2-deep pipeline over the wave's 4 n ----
    GR A, B;
    gather_issue(A, idx_s, w * 4 + 0, b, Kt8, Vt16, coord, g, sub, lane);
    gather_issue(B, idx_s, w * 4 + 1, b, Kt8, Vt16, coord, g, sub, lane);
    compute(w * 4 + 0, A);
    gather_issue(A, idx_s, w * 4 + 2, b, Kt8, Vt16, coord, g, sub, lane);
    compute(w * 4 + 1, B);
    gather_issue(B, idx_s, w * 4 + 3, b, Kt8, Vt16, coord, g, sub, lane);
    compute(w * 4 + 2, A);
    compute(w * 4 + 3, B);

    __syncthreads();

    // ---- coalesced transposed store: out[b][c][n0+col] ----
    {
        const int col = t & 15;
        const int r0  = (t >> 4) * 8;
        #pragma unroll
        for (int r = 0; r < 8; ++r)
            out[((size_t)(b * C_ + r0 + r)) * N_ + n0 + col] = ot[r0 + r][col];
    }
}

// ---------------------------------------------------------------------------
extern "C" void kernel_launch(void* const* d_in, const int* in_sizes, int n_in,
                              void* d_out, int out_size, void* d_ws, size_t ws_size,
                              hipStream_t stream) {
    const float* coord = (const float*)d_in[0];
    const float* spa   = (const float*)d_in[1];
    const float* spe   = (const float*)d_in[2];
    const int*   nbr   = (const int*)  d_in[3];
    const float* wq    = (const float*)d_in[4];
    const float* wk    = (const float*)d_in[5];
    const float* wv    = (const float*)d_in[6];
    const float* wvb   = (const float*)d_in[7];
    const float* pw1   = (const float*)d_in[8];
    const float* pb1   = (const float*)d_in[9];
    const float* pg    = (const float*)d_in[10];
    const float* pbeta = (const float*)d_in[11];
    const float* pmu   = (const float*)d_in[12];
    const float* pvar  = (const float*)d_in[13];
    const float* pw2   = (const float*)d_in[14];
    const float* pb2   = (const float*)d_in[15];
    const float* sw1   = (const float*)d_in[16];
    const float* sb1   = (const float*)d_in[17];
    const float* sg    = (const float*)d_in[18];
    const float* sbeta = (const float*)d_in[19];
    const float* smu   = (const float*)d_in[20];
    const float* svar  = (const float*)d_in[21];
    const float* sw2   = (const float*)d_in[22];
    const float* sb2   = (const float*)d_in[23];
    float* out = (float*)d_out;

    // Workspace: Qt bf16 (8 MiB), Vt bf16 (8 MiB), Kt fp8 (4 MiB)
    ushort*  Qt16 = (ushort*)d_ws;
    ushort*  Vt16 = Qt16 + (size_t)B_ * N_ * C_;
    uint8_t* Kt8  = (uint8_t*)(Vt16 + (size_t)B_ * N_ * C_);

    qkv_gemm<<<dim3(N_ / 128, B_, 2), 512, 0, stream>>>(
        spa, spe, wq, wk, wv, wvb, Qt16, Kt8, Vt16);

    attn_fuse<<<dim3(B_ * N_ / 16), 256, 0, stream>>>(
        coord, nbr, Qt16, Kt8, Vt16,
        pw1, pb1, pg, pbeta, pmu, pvar, pw2, pb2,
        sw1, sb1, sg, sbeta, smu, svar, sw2, sb2,
        out);
}

// Round 11
// 170.905 us; speedup vs baseline: 1.0127x; 1.0127x over previous
//
#include <hip/hip_runtime.h>
#include <cstdint>
#include <cstddef>

// Problem constants (fixed by the bench harness)
#define B_ 2
#define N_ 16384
#define K_ 16
#define C_ 128

typedef __attribute__((ext_vector_type(8))) short  bf16x8;
typedef __attribute__((ext_vector_type(4))) float  f32x4;

// bf16 (ushort bits) -> fp32, exact
__device__ __forceinline__ float bfu_lo(uint32_t w) { return __uint_as_float(w << 16); }
__device__ __forceinline__ float bfu_hi(uint32_t w) { return __uint_as_float(w & 0xffff0000u); }

// fp32 -> bf16 bits, round-to-nearest-even
__device__ __forceinline__ ushort f32_to_bf16_rne(float x) {
    uint32_t u = __float_as_uint(x);
    u += 0x7FFFu + ((u >> 16) & 1u);
    return (ushort)(u >> 16);
}
__device__ __forceinline__ uint32_t pack_bf16x2(float lo, float hi) {
    return (uint32_t)f32_to_bf16_rne(lo) | ((uint32_t)f32_to_bf16_rne(hi) << 16);
}

// fp8 e5m2 via the f16-prefix trick (e5m2 = top byte of IEEE f16).
__device__ __forceinline__ uint32_t e5m2_enc(float x) {
    union { _Float16 h; ushort u; } cv;
    cv.h = (_Float16)x;                       // RNE f32->f16 (hw)
    ushort h = (ushort)(cv.u + 0x7Fu + ((cv.u >> 8) & 1u));  // RNE to top byte
    return (uint32_t)(h >> 8) & 0xFFu;
}
__device__ __forceinline__ float e5m2_dec(uint32_t byteval) {
    union { _Float16 h; ushort u; } cv;
    cv.u = (ushort)(byteval << 8);
    return (float)cv.h;
}

// LDS swizzle: element offset of (row, c) in a [128 row][128 c] bf16 tile.
__device__ __forceinline__ int xswz(int row, int c) {
    return row * 128 + ((((c >> 3) ^ (row & 7)) << 3) | (c & 7));
}

// ---------------------------------------------------------------------------
// Kernel 1: QKV projections via MFMA (bf16 in, fp32 acc).  (round-9 best)
//   Q,V -> bf16; K -> fp8 e5m2. Block tile 128o x 128n, 512 thr = 8 waves.
//   W and X both staged in LDS; inner loop pure ds_read_b128 + MFMA.
// grid (N/128, B, 3).
// ---------------------------------------------------------------------------
__global__ __launch_bounds__(512) void qkv_gemm(
    const float* __restrict__ spa, const float* __restrict__ spe,
    const float* __restrict__ wq, const float* __restrict__ wk,
    const float* __restrict__ wv, const float* __restrict__ wvb,
    ushort* __restrict__ Qt16, uint8_t* __restrict__ Kt8, ushort* __restrict__ Vt16)
{
    const int nt    = blockIdx.x * 128;
    const int b     = blockIdx.y;
    const int which = blockIdx.z;
    const float* X = (which == 0) ? spa : spe;
    const float* W = (which == 0) ? wq : (which == 1 ? wk : wv);

    __shared__ ushort xs[128 * 128];
    __shared__ ushort ws[128 * 128];

    const int t    = threadIdx.x;
    const int w    = t >> 6;
    const int lane = t & 63;
    const int l15  = lane & 15;
    const int l4   = lane >> 4;
    const int ow   = (w & 3) * 32;
    const int nw   = (w >> 2) * 64;

    {
        const int r  = t >> 2;
        const int c0 = (t & 3) * 32;
        const float* srcw = W + r * C_ + c0;
        #pragma unroll
        for (int q = 0; q < 4; ++q) {
            float4 a  = *(const float4*)(srcw + q * 8);
            float4 b4 = *(const float4*)(srcw + q * 8 + 4);
            uint4 pk;
            pk.x = pack_bf16x2(a.x, a.y);
            pk.y = pack_bf16x2(a.z, a.w);
            pk.z = pack_bf16x2(b4.x, b4.y);
            pk.w = pack_bf16x2(b4.z, b4.w);
            *(uint4*)&ws[xswz(r, c0 + q * 8)] = pk;
        }
    }
    {
        const int c  = t >> 2;
        const int nq = (t & 3) * 32;
        const float* xrow = X + ((size_t)b * C_ + c) * N_ + nt + nq;
        #pragma unroll
        for (int q = 0; q < 8; ++q) {
            float4 v = ((const float4*)xrow)[q];
            const int n = nq + q * 4;
            xs[xswz(n + 0, c)] = f32_to_bf16_rne(v.x);
            xs[xswz(n + 1, c)] = f32_to_bf16_rne(v.y);
            xs[xswz(n + 2, c)] = f32_to_bf16_rne(v.z);
            xs[xswz(n + 3, c)] = f32_to_bf16_rne(v.w);
        }
    }
    __syncthreads();

    f32x4 acc[2][4];
    #pragma unroll
    for (int of = 0; of < 2; ++of)
        #pragma unroll
        for (int nf = 0; nf < 4; ++nf)
            acc[of][nf] = (f32x4){0.f, 0.f, 0.f, 0.f};

    #pragma unroll
    for (int kc = 0; kc < 4; ++kc) {
        const int cb = kc * 32 + l4 * 8;
        bf16x8 afr[2];
        #pragma unroll
        for (int of = 0; of < 2; ++of)
            afr[of] = *(__shared__ bf16x8*)&ws[xswz(ow + of * 16 + l15, cb)];
        bf16x8 bfr[4];
        #pragma unroll
        for (int nf = 0; nf < 4; ++nf)
            bfr[nf] = *(__shared__ bf16x8*)&xs[xswz(nw + nf * 16 + l15, cb)];
        #pragma unroll
        for (int of = 0; of < 2; ++of)
            #pragma unroll
            for (int nf = 0; nf < 4; ++nf)
                acc[of][nf] = __builtin_amdgcn_mfma_f32_16x16x32_bf16(
                    afr[of], bfr[nf], acc[of][nf], 0, 0, 0);
    }

    #pragma unroll
    for (int of = 0; of < 2; ++of) {
        const int o0r = ow + of * 16 + l4 * 4;
        if (which == 1) {
            #pragma unroll
            for (int nf = 0; nf < 4; ++nf) {
                const int n = nt + nw + nf * 16 + l15;
                uint32_t w8 = e5m2_enc(acc[of][nf][0])
                            | (e5m2_enc(acc[of][nf][1]) << 8)
                            | (e5m2_enc(acc[of][nf][2]) << 16)
                            | (e5m2_enc(acc[of][nf][3]) << 24);
                *(uint32_t*)(Kt8 + ((size_t)b * N_ + n) * C_ + o0r) = w8;
            }
        } else {
            ushort* Out = (which == 0) ? Qt16 : Vt16;
            float4 bv = make_float4(0.f, 0.f, 0.f, 0.f);
            if (which == 2) bv = *(const float4*)(wvb + o0r);
            #pragma unroll
            for (int nf = 0; nf < 4; ++nf) {
                const int n = nt + nw + nf * 16 + l15;
                uint2 pk;
                pk.x = pack_bf16x2(acc[of][nf][0] + bv.x, acc[of][nf][1] + bv.y);
                pk.y = pack_bf16x2(acc[of][nf][2] + bv.z, acc[of][nf][3] + bv.w);
                *(uint2*)(Out + ((size_t)b * N_ + n) * C_ + o0r) = pk;
            }
        }
    }
}

// ---------------------------------------------------------------------------
// Kernel 2: gather + scores + softmax + weighted V-sum. (round-9 best)
// 2-deep gather pipeline across n (sets A/B, named regs).
// block 256 = 4 waves; wave handles 4 n; 16-n tile per block.
// ---------------------------------------------------------------------------
struct GR {
    uint4    ka, kb;          // 32 fp8 K channels for this lane's k-group
    uint32_t vv[16];          // V bf16-pair per k, channels 2l/2l+1
    float    nc0, nc1, nc2;   // neighbor coords for this lane's k-group
};

__device__ __forceinline__ void gather_issue(
    GR& g2, const int (*idx_s)[16], int nl, int b,
    const uint8_t* __restrict__ Kt8, const ushort* __restrict__ Vt16,
    const float* __restrict__ coord, int gk, int sub, int lane)
{
    const int idxg = idx_s[nl][gk];
    const uint4* kp = (const uint4*)(Kt8 + ((size_t)(b * N_ + idxg)) * C_ + sub * 32);
    g2.ka = kp[0];
    g2.kb = kp[1];
    #pragma unroll
    for (int k = 0; k < 16; ++k) {
        const int vid = idx_s[nl][k];
        g2.vv[k] = ((const uint32_t*)(Vt16 + ((size_t)(b * N_ + vid)) * C_))[lane];
    }
    const float* ncp = coord + ((size_t)(b * N_ + idxg)) * 3;
    g2.nc0 = ncp[0];
    g2.nc1 = ncp[1];
    g2.nc2 = ncp[2];
}

__global__ __launch_bounds__(256) void attn_fuse(
    const float* __restrict__ coord, const int* __restrict__ nbr,
    const ushort* __restrict__ Qt16, const uint8_t* __restrict__ Kt8,
    const ushort* __restrict__ Vt16,
    const float* __restrict__ pw1, const float* __restrict__ pb1,
    const float* __restrict__ pg,  const float* __restrict__ pbeta,
    const float* __restrict__ pmu, const float* __restrict__ pvar,
    const float* __restrict__ pw2, const float* __restrict__ pb2,
    const float* __restrict__ sw1, const float* __restrict__ sb1,
    const float* __restrict__ sg,  const float* __restrict__ sbeta,
    const float* __restrict__ smu, const float* __restrict__ svar,
    const float* __restrict__ sw2, const float* __restrict__ sb2,
    float* __restrict__ out)
{
    const int bid  = blockIdx.x;
    const int b    = bid >> 10;               // 1024 blocks per batch
    const int n0   = (bid & 1023) << 4;       // 16-n tile
    const int t    = threadIdx.x;
    const int w    = t >> 6;                  // wave 0..3
    const int lane = t & 63;
    const int g    = lane >> 2;               // k index 0..15
    const int sub  = lane & 3;                // channel quarter

    __shared__ float qs[16][132];
    __shared__ int   idx_s[16][16];
    __shared__ float cs[16][3];
    __shared__ float ot[128][17];

    // ---- stage ----
    {
        const int n = t >> 4, c0 = (t & 15) * 8;
        uint4 qw = *(const uint4*)(Qt16 + ((size_t)(b * N_ + n0 + n)) * C_ + c0);
        qs[n][c0 + 0] = bfu_lo(qw.x); qs[n][c0 + 1] = bfu_hi(qw.x);
        qs[n][c0 + 2] = bfu_lo(qw.y); qs[n][c0 + 3] = bfu_hi(qw.y);
        qs[n][c0 + 4] = bfu_lo(qw.z); qs[n][c0 + 5] = bfu_hi(qw.z);
        qs[n][c0 + 6] = bfu_lo(qw.w); qs[n][c0 + 7] = bfu_hi(qw.w);
        idx_s[t >> 4][t & 15] = nbr[((size_t)(b * N_ + n0 + (t >> 4))) * K_ + (t & 15)];
        if (t < 48) cs[t / 3][t % 3] = coord[((size_t)(b * N_ + n0 + t / 3)) * 3 + (t % 3)];
    }
    __syncthreads();

    // ---- uniform params (BN folded) ----
    float pinv[3], pofs[3], w1r[3][3], w2r[3], pb1r[3];
    #pragma unroll
    for (int o = 0; o < 3; ++o) {
        float inv = pg[o] / sqrtf(pvar[o] + 1e-5f);
        pinv[o] = inv;
        pofs[o] = pbeta[o] - pmu[o] * inv;
        pb1r[o] = pb1[o];
        w2r[o]  = pw2[o];
        #pragma unroll
        for (int i2 = 0; i2 < 3; ++i2) w1r[o][i2] = pw1[o * 3 + i2];
    }
    const float pb2v = pb2[0];
    float sinv[2], sofs[2], sb1r[2];
    #pragma unroll
    for (int o = 0; o < 2; ++o) {
        float inv = sg[o] / sqrtf(svar[o] + 1e-5f);
        sinv[o] = inv;
        sofs[o] = sbeta[o] - smu[o] * inv;
        sb1r[o] = sb1[o];
    }
    const float sw1r[4] = {sw1[0], sw1[1], sw1[2], sw1[3]};
    const float sw2r[2] = {sw2[0], sw2[1]};
    const float sb2v = sb2[0];
    const float inv_sqrtC = 0.088388347648318447f;  // 1/sqrt(128)

    // compute for one n using a gather set (static indexing)
    auto compute = [&](int nl, GR& gr) {
        const float* qrow = &qs[nl][sub * 32];
        float acc = 0.f;
        {
            const uint32_t wds[8] = {gr.ka.x, gr.ka.y, gr.ka.z, gr.ka.w,
                                     gr.kb.x, gr.kb.y, gr.kb.z, gr.kb.w};
            #pragma unroll
            for (int j = 0; j < 8; ++j) {
                const uint32_t ww = wds[j];
                acc = fmaf(qrow[j * 4 + 0], e5m2_dec(ww & 0xffu), acc);
                acc = fmaf(qrow[j * 4 + 1], e5m2_dec((ww >> 8) & 0xffu), acc);
                acc = fmaf(qrow[j * 4 + 2], e5m2_dec((ww >> 16) & 0xffu), acc);
                acc = fmaf(qrow[j * 4 + 3], e5m2_dec(ww >> 24), acc);
            }
        }
        acc += __shfl_xor(acc, 1);
        acc += __shfl_xor(acc, 2);
        const float sfeat = acc * inv_sqrtC;

        float d0 = gr.nc0 - cs[nl][0], d1 = gr.nc1 - cs[nl][1], d2 = gr.nc2 - cs[nl][2];
        float g0 = expf(-2.f * d0 * d0);
        float g1 = expf(-2.f * d1 * d1);
        float g2 = expf(-2.f * d2 * d2);
        float h0 = fmaf(w1r[0][0], g0, fmaf(w1r[0][1], g1, fmaf(w1r[0][2], g2, pb1r[0])));
        float h1 = fmaf(w1r[1][0], g0, fmaf(w1r[1][1], g1, fmaf(w1r[1][2], g2, pb1r[1])));
        float h2 = fmaf(w1r[2][0], g0, fmaf(w1r[2][1], g1, fmaf(w1r[2][2], g2, pb1r[2])));
        h0 = fmaxf(fmaf(h0, pinv[0], pofs[0]), 0.f);
        h1 = fmaxf(fmaf(h1, pinv[1], pofs[1]), 0.f);
        h2 = fmaxf(fmaf(h2, pinv[2], pofs[2]), 0.f);
        const float scoord = fmaf(w2r[0], h0, fmaf(w2r[1], h1, fmaf(w2r[2], h2, pb2v)));

        float t0 = fmaf(sw1r[0], scoord, fmaf(sw1r[1], sfeat, sb1r[0]));
        t0 = fmaxf(fmaf(t0, sinv[0], sofs[0]), 0.f);
        float t1 = fmaf(sw1r[2], scoord, fmaf(sw1r[3], sfeat, sb1r[1]));
        t1 = fmaxf(fmaf(t1, sinv[1], sofs[1]), 0.f);
        float s = fmaf(sw2r[0], t0, fmaf(sw2r[1], t1, sb2v));

        float m = s;
        m = fmaxf(m, __shfl_xor(m, 4));
        m = fmaxf(m, __shfl_xor(m, 8));
        m = fmaxf(m, __shfl_xor(m, 16));
        m = fmaxf(m, __shfl_xor(m, 32));
        float e = expf(s - m);
        float den = e;
        den += __shfl_xor(den, 4);
        den += __shfl_xor(den, 8);
        den += __shfl_xor(den, 16);
        den += __shfl_xor(den, 32);
        const float attn = e / den;

        float a0 = 0.f, a1 = 0.f;
        #pragma unroll
        for (int k = 0; k < 16; ++k) {
            const float ak = __shfl(attn, k << 2);
            a0 = fmaf(ak, bfu_lo(gr.vv[k]), a0);
            a1 = fmaf(ak, bfu_hi(gr.vv[k]), a1);
        }
        ot[2 * lane][nl]     = a0;
        ot[2 * lane + 1][nl] = a1;
    };

    // ---- 2-deep pipeline over the wave's 4 n ----
    GR A, B;
    gather_issue(A, idx_s, w * 4 + 0, b, Kt8, Vt16, coord, g, sub, lane);
    gather_issue(B, idx_s, w * 4 + 1, b, Kt8, Vt16, coord, g, sub, lane);
    compute(w * 4 + 0, A);
    gather_issue(A, idx_s, w * 4 + 2, b, Kt8, Vt16, coord, g, sub, lane);
    compute(w * 4 + 1, B);
    gather_issue(B, idx_s, w * 4 + 3, b, Kt8, Vt16, coord, g, sub, lane);
    compute(w * 4 + 2, A);
    compute(w * 4 + 3, B);

    __syncthreads();

    // ---- coalesced transposed store: out[b][c][n0+col] ----
    {
        const int col = t & 15;
        const int r0  = (t >> 4) * 8;
        #pragma unroll
        for (int r = 0; r < 8; ++r)
            out[((size_t)(b * C_ + r0 + r)) * N_ + n0 + col] = ot[r0 + r][col];
    }
}

// ---------------------------------------------------------------------------
extern "C" void kernel_launch(void* const* d_in, const int* in_sizes, int n_in,
                              void* d_out, int out_size, void* d_ws, size_t ws_size,
                              hipStream_t stream) {
    const float* coord = (const float*)d_in[0];
    const float* spa   = (const float*)d_in[1];
    const float* spe   = (const float*)d_in[2];
    const int*   nbr   = (const int*)  d_in[3];
    const float* wq    = (const float*)d_in[4];
    const float* wk    = (const float*)d_in[5];
    const float* wv    = (const float*)d_in[6];
    const float* wvb   = (const float*)d_in[7];
    const float* pw1   = (const float*)d_in[8];
    const float* pb1   = (const float*)d_in[9];
    const float* pg    = (const float*)d_in[10];
    const float* pbeta = (const float*)d_in[11];
    const float* pmu   = (const float*)d_in[12];
    const float* pvar  = (const float*)d_in[13];
    const float* pw2   = (const float*)d_in[14];
    const float* pb2   = (const float*)d_in[15];
    const float* sw1   = (const float*)d_in[16];
    const float* sb1   = (const float*)d_in[17];
    const float* sg    = (const float*)d_in[18];
    const float* sbeta = (const float*)d_in[19];
    const float* smu   = (const float*)d_in[20];
    const float* svar  = (const float*)d_in[21];
    const float* sw2   = (const float*)d_in[22];
    const float* sb2   = (const float*)d_in[23];
    float* out = (float*)d_out;

    // Workspace: Qt bf16 (8 MiB), Vt bf16 (8 MiB), Kt fp8 (4 MiB)
    ushort*  Qt16 = (ushort*)d_ws;
    ushort*  Vt16 = Qt16 + (size_t)B_ * N_ * C_;
    uint8_t* Kt8  = (uint8_t*)(Vt16 + (size_t)B_ * N_ * C_);

    qkv_gemm<<<dim3(N_ / 128, B_, 3), 512, 0, stream>>>(
        spa, spe, wq, wk, wv, wvb, Qt16, Kt8, Vt16);

    attn_fuse<<<dim3(B_ * N_ / 16), 256, 0, stream>>>(
        coord, nbr, Qt16, Kt8, Vt16,
        pw1, pb1, pg, pbeta, pmu, pvar, pw2, pb2,
        sw1, sb1, sg, sbeta, smu, svar, sw2, sb2,
        out);
}